// Round 6
// baseline (302.455 us; speedup 1.0000x reference)
//
#include <hip/hip_runtime.h>
#include <hip/hip_bf16.h>
#include <stdint.h>

typedef unsigned short u16;
typedef unsigned int u32;
typedef short s16x8 __attribute__((ext_vector_type(8)));
typedef float f32x4 __attribute__((ext_vector_type(4)));

#define S_LEN 2048
#define SCALE 0.088388347648318447f
#define NEG_BIG (-1.0e9f)
#define WAITV(N) asm volatile("s_waitcnt vmcnt(" #N ")" ::: "memory")
#define FENCE() asm volatile("" ::: "memory")

__device__ __forceinline__ u16 f2bf(float f) {
  unsigned u = __builtin_bit_cast(unsigned, f);
  u += 0x7fffu + ((u >> 16) & 1u);
  return (u16)(u >> 16);
}
__device__ __forceinline__ float bf2f(u16 h) {
  unsigned u = ((unsigned)h) << 16;
  return __builtin_bit_cast(float, u);
}
__device__ __forceinline__ void gload16(const void* g, void* l) {
  __builtin_amdgcn_global_load_lds((const __attribute__((address_space(1))) void*)g,
                                   (__attribute__((address_space(3))) void*)l, 16, 0, 0);
}

// ---------------- fused preprocessing: cvt(hs) + 4 weight transposes ----------------
__device__ __forceinline__ void do_transpose(const float* __restrict__ in, u16* __restrict__ out,
                                             int R, int C, int rel, int tilesx) {
  __shared__ float tile[32][33];
  int bx = (rel % tilesx) * 32, by = (rel / tilesx) * 32;
  int tx = threadIdx.x & 31, ty = threadIdx.x >> 5;
#pragma unroll
  for (int i = 0; i < 4; i++)
    tile[ty + i * 8][tx] = in[(size_t)(by + ty + i * 8) * C + bx + tx];
  __syncthreads();
#pragma unroll
  for (int i = 0; i < 4; i++)
    out[(size_t)(bx + ty + i * 8) * R + by + tx] = f2bf(tile[tx][ty + i * 8]);
}

__global__ __launch_bounds__(256) void prep_k(const float* __restrict__ hs, u16* __restrict__ hsb,
                                              const float* __restrict__ wq, const float* __restrict__ wk,
                                              const float* __restrict__ wv, const float* __restrict__ wo,
                                              u16* __restrict__ wqkvT, u16* __restrict__ woT) {
  int bid = blockIdx.x;
  if (bid < 4096) {
    int i = bid * 256 + threadIdx.x;
    float4 v = ((const float4*)hs)[i];
    ushort4 o;
    o.x = f2bf(v.x); o.y = f2bf(v.y); o.z = f2bf(v.z); o.w = f2bf(v.w);
    ((ushort4*)hsb)[i] = o;
  } else if (bid < 8192) {
    do_transpose(wq, wqkvT, 2048, 2048, bid - 4096, 64);
  } else if (bid < 10240) {
    do_transpose(wk, wqkvT + (size_t)2048 * 2048, 2048, 1024, bid - 8192, 32);
  } else if (bid < 12288) {
    do_transpose(wv, wqkvT + (size_t)3072 * 2048, 2048, 1024, bid - 10240, 32);
  } else {
    do_transpose(wo, woT, 2048, 2048, bid - 12288, 64);
  }
}

// ---------------- GEMM: C[M,N] = A[M,K]*BT[N,K]^T, BN=128, BK=64 ----------------
// 3-deep LDS pipeline: prefetch depth 2, counted vmcnt -> loads span 2 compute iters.
// BM=256: 512 thr / 8 waves (4m x 2n), LDS 144KB. BM=128: 256 thr / 4 waves, LDS 96KB.
template <int BM, int F32OUT>
__global__ __launch_bounds__(BM == 256 ? 512 : 256) void gemm3_k(const u16* __restrict__ A,
                                                                 const u16* __restrict__ BT,
                                                                 void* __restrict__ Cout, int N, int K) {
  constexpr int NT = (BM == 256) ? 512 : 256;
  constexpr int ALOADS = BM * 8 / NT;   // 4
  constexpr int BLOADS = 128 * 8 / NT;  // 2 (BM=256) or 4 (BM=128)
  __shared__ u16 lA[3][BM * 64];
  __shared__ u16 lB[3][128 * 64];
  int tid = threadIdx.x;
  int w = tid >> 6, l = tid & 63, r = l & 15, g = l >> 4;
  int tn = blockIdx.x, tm = blockIdx.y;
  int wm = w >> 1, wn = w & 1;
  f32x4 zf = {0.f, 0.f, 0.f, 0.f};
  f32x4 acc[4][4];
#pragma unroll
  for (int mi = 0; mi < 4; mi++)
#pragma unroll
    for (int ni = 0; ni < 4; ni++) acc[mi][ni] = zf;
  int nkt = K >> 6;

  auto stage = [&](int bi, int kt) {
#pragma unroll
    for (int i = 0; i < ALOADS; i++) {
      int c = i * NT + tid;
      int row = c >> 3;
      int sb = ((c & 7) * 16) ^ ((row & 7) << 4);
      gload16(A + (size_t)(tm * BM + row) * K + kt * 64 + (sb >> 1), (char*)(&lA[bi][0]) + c * 16);
    }
#pragma unroll
    for (int i = 0; i < BLOADS; i++) {
      int c = i * NT + tid;
      int row = c >> 3;
      int sb = ((c & 7) * 16) ^ ((row & 7) << 4);
      gload16(BT + (size_t)(tn * 128 + row) * K + kt * 64 + (sb >> 1), (char*)(&lB[bi][0]) + c * 16);
    }
  };
  auto compute = [&](int bi) {
    const char* AB = (const char*)&lA[bi][0];
    const char* BB = (const char*)&lB[bi][0];
#pragma unroll
    for (int kk = 0; kk < 2; kk++) {
      s16x8 af[4], bfr[4];
#pragma unroll
      for (int mi = 0; mi < 4; mi++) {
        int row = wm * 64 + mi * 16 + r;
        af[mi] = *(const s16x8*)(AB + ((row * 128 + kk * 64 + g * 16) ^ ((r & 7) << 4)));
      }
#pragma unroll
      for (int ni = 0; ni < 4; ni++) {
        int row = wn * 64 + ni * 16 + r;
        bfr[ni] = *(const s16x8*)(BB + ((row * 128 + kk * 64 + g * 16) ^ ((r & 7) << 4)));
      }
#pragma unroll
      for (int mi = 0; mi < 4; mi++)
#pragma unroll
        for (int ni = 0; ni < 4; ni++)
          acc[mi][ni] = __builtin_amdgcn_mfma_f32_16x16x32_bf16(af[mi], bfr[ni], acc[mi][ni], 0, 0, 0);
    }
  };

  stage(0, 0);
  stage(1, 1);
  int bi = 0, pf = 2;
  for (int kt = 0; kt < nkt; ++kt) {
    if (kt + 2 < nkt) {
      stage(pf, kt + 2);  // depth-2 prefetch: 2 full compute iters to land
      if (BM == 256) WAITV(12); else WAITV(16);  // drain only stage(kt)
    } else if (kt + 1 < nkt) {
      if (BM == 256) WAITV(6); else WAITV(8);
    } else {
      WAITV(0);
    }
    FENCE();
    __builtin_amdgcn_s_barrier();  // buf bi consistent across waves
    FENCE();
    __builtin_amdgcn_s_setprio(1);
    compute(bi);
    __builtin_amdgcn_s_setprio(0);
    FENCE();
    __builtin_amdgcn_s_barrier();  // readers done before bi gets overwritten (at kt+3)
    FENCE();
    bi = (bi == 2) ? 0 : bi + 1;
    pf = (pf == 2) ? 0 : pf + 1;
  }

#pragma unroll
  for (int mi = 0; mi < 4; mi++) {
#pragma unroll
    for (int ni = 0; ni < 4; ni++) {
#pragma unroll
      for (int j = 0; j < 4; j++) {
        int row = tm * BM + wm * 64 + mi * 16 + g * 4 + j;
        int col = tn * 128 + wn * 64 + ni * 16 + r;
        if (F32OUT)
          ((float*)Cout)[(size_t)row * N + col] = acc[mi][ni][j];
        else
          ((u16*)Cout)[(size_t)row * N + col] = f2bf(acc[mi][ni][j]);
      }
    }
  }
}

// ---------------- fused post: RMSNorm+RoPE (Q pre-scaled, K), V transpose, cross zero ----------------
__global__ __launch_bounds__(256) void post_k(const u16* __restrict__ qkv, const float* __restrict__ qw,
                                              const float* __restrict__ kw, const float* __restrict__ cosT,
                                              const float* __restrict__ sinT, u16* __restrict__ Qb,
                                              u16* __restrict__ Kb, u16* __restrict__ Vt,
                                              float* __restrict__ cross) {
  int bid = blockIdx.x;
  int tid = threadIdx.x;
  if (bid == 0 && tid < 16) cross[tid] = 0.f;
  if (bid < 16384) {
    int gw = bid * 4 + (tid >> 6);
    int l = tid & 63;
    int s = gw >> 5, slot = gw & 31;
    if (slot >= 24) return;
    const float* nw;
    const u16* src;
    u16* dst;
    float qs;
    if (slot < 16) {
      src = qkv + (size_t)s * 4096 + slot * 128;
      nw = qw;
      dst = Qb + ((size_t)slot * S_LEN + s) * 128;
      qs = SCALE;  // fold 1/sqrt(D) into Q
    } else {
      int hk = slot - 16;
      src = qkv + (size_t)s * 4096 + 2048 + hk * 128;
      nw = kw;
      dst = Kb + ((size_t)hk * S_LEN + s) * 128;
      qs = 1.0f;
    }
    ushort2 xv = ((const ushort2*)src)[l];
    float x0 = bf2f(xv.x), x1 = bf2f(xv.y);
    float ss = x0 * x0 + x1 * x1;
#pragma unroll
    for (int off = 1; off < 64; off <<= 1) ss += __shfl_xor(ss, off);
    float inv = rsqrtf(ss * (1.0f / 128.0f) + 1e-6f);
    int d0 = l * 2;
    float xn0 = x0 * inv * nw[d0], xn1 = x1 * inv * nw[d0 + 1];
    float p0 = __shfl_xor(xn0, 32), p1 = __shfl_xor(xn1, 32);
    float c0 = cosT[s * 128 + d0], c1 = cosT[s * 128 + d0 + 1];
    float sn0 = sinT[s * 128 + d0], sn1 = sinT[s * 128 + d0 + 1];
    float sg = (l < 32) ? -1.0f : 1.0f;
    ushort2 o;
    o.x = f2bf((xn0 * c0 + sg * p0 * sn0) * qs);
    o.y = f2bf((xn1 * c1 + sg * p1 * sn1) * qs);
    ((ushort2*)dst)[l] = o;
  } else {
    __shared__ u16 t[64][66];
    int rel = bid - 16384;
    int c0 = (rel & 15) * 64, s0 = (rel >> 4) * 64;
    int tx = tid & 63, ty = tid >> 6;
#pragma unroll
    for (int i = 0; i < 16; i++)
      t[ty + i * 4][tx] = qkv[(size_t)(s0 + ty + i * 4) * 4096 + 3072 + c0 + tx];
    __syncthreads();
#pragma unroll
    for (int i = 0; i < 16; i++)
      Vt[(size_t)(c0 + ty + i * 4) * 2048 + s0 + tx] = t[tx][ty + i * 4];
  }
}

// ---------------- flash attention + cross-score ----------------
// grid 256 = 16h x 16a; each block SERIALLY does q-tiles {a, 31-a} -> exactly 33 KV-iters
// per block, uniform by construction (no dispatch-order assumptions).
__global__ __launch_bounds__(256, 2) void attn_k(const u16* __restrict__ Qb, const u16* __restrict__ Kb,
                                                 const u16* __restrict__ Vt, u16* __restrict__ AO,
                                                 float* __restrict__ cross) {
  __shared__ u16 Kl[2][64 * 128];
  __shared__ u16 Vl[2][128 * 64];
  __shared__ u16 Pl[4][16 * 64];
  int tid = threadIdx.x;
  int w = tid >> 6, l = tid & 63, r = l & 15, g = l >> 4;
  int bid = blockIdx.x;
  int h = bid & 15, a = bid >> 4;
  int hk = h >> 1;
  char* PlB = (char*)(&Pl[w][0]);

  int skrow = tid >> 4;
  int skoff = (tid & 15) * 16;
  int svrow = tid >> 3;
  int svoff = (tid & 7) * 16;
  auto stage = [&](int bi, int kb) {
#pragma unroll
    for (int i = 0; i < 4; i++) {
      int k = i * 16 + skrow;
      int sb = skoff ^ ((k & 7) << 4);
      gload16(Kb + (((size_t)hk * S_LEN + kb * 64 + k) << 7) + (sb >> 1),
              (char*)(&Kl[bi][0]) + (i * 256 + tid) * 16);
    }
#pragma unroll
    for (int i = 0; i < 4; i++) {
      int d = i * 32 + svrow;
      int sb = svoff ^ ((d & 7) << 4);
      gload16(Vt + (((size_t)hk * 128 + d) << 11) + kb * 64 + (sb >> 1),
              (char*)(&Vl[bi][0]) + (i * 256 + tid) * 16);
    }
  };

  f32x4 zf = {0.f, 0.f, 0.f, 0.f};
  for (int ph = 0; ph < 2; ++ph) {
    int qb = ph ? (31 - a) : a;
    int qrow = qb * 64 + w * 16 + r;
    s16x8 qf[4];
#pragma unroll
    for (int kc = 0; kc < 4; kc++)
      qf[kc] = *(const s16x8*)&Qb[((size_t)h * S_LEN + qrow) * 128 + kc * 32 + g * 8];
    f32x4 o_[8];
#pragma unroll
    for (int dt = 0; dt < 8; dt++) o_[dt] = zf;
    float m_ = -3e38f, l_ = 0.f, vs_ = 0.f;

    stage(0, 0);
    int buf = 0;
    for (int kb = 0; kb <= qb; ++kb) {
      if (kb < qb) {
        stage(buf ^ 1, kb + 1);  // 8 new loads; wait for the older 8 (this buf):
        WAITV(8);
      } else {
        WAITV(0);
      }
      FENCE();
      __builtin_amdgcn_s_barrier();
      FENCE();
      const char* KB = (const char*)&Kl[buf][0];
      const char* VB = (const char*)&Vl[buf][0];
      // ---- S^T = K Q^T : sa[ct][j] = S[k = kb*64+ct*16+g*4+j][q = qrow] (pre-scaled) ----
      f32x4 sa[4];
      __builtin_amdgcn_s_setprio(1);
#pragma unroll
      for (int ct = 0; ct < 4; ct++) {
        sa[ct] = zf;
#pragma unroll
        for (int kc = 0; kc < 4; kc++) {
          int kbyte = (((ct * 16 + r) * 256) + kc * 64 + g * 16) ^ ((r & 7) << 4);
          sa[ct] = __builtin_amdgcn_mfma_f32_16x16x32_bf16(*(const s16x8*)(KB + kbyte), qf[kc], sa[ct], 0, 0, 0);
        }
      }
      __builtin_amdgcn_s_setprio(0);
      // ---- mask + online softmax (in-lane; defer-max THR=8) ----
      float sv[4][4];
      float rmax = -3e38f;
      if (kb == qb) {
        int kb0 = kb * 64 + g * 4;
#pragma unroll
        for (int ct = 0; ct < 4; ct++)
#pragma unroll
          for (int j = 0; j < 4; j++) {
            float x = sa[ct][j] + ((kb0 + ct * 16 + j) > qrow ? NEG_BIG : 0.f);
            sv[ct][j] = x;
            rmax = fmaxf(rmax, x);
          }
      } else {
#pragma unroll
        for (int ct = 0; ct < 4; ct++)
#pragma unroll
          for (int j = 0; j < 4; j++) {
            float x = sa[ct][j];
            sv[ct][j] = x;
            rmax = fmaxf(rmax, x);
          }
      }
      rmax = fmaxf(rmax, __shfl_xor(rmax, 16));
      rmax = fmaxf(rmax, __shfl_xor(rmax, 32));
      if (__any(rmax > m_ + 8.f)) {
        float mn = fmaxf(m_, rmax);
        float sc = __expf(m_ - mn);
        m_ = mn;
        l_ *= sc;
        vs_ *= sc;
        float scb[4];
#pragma unroll
        for (int j = 0; j < 4; j++) scb[j] = __shfl(sc, g * 4 + j);
#pragma unroll
        for (int dt = 0; dt < 8; dt++)
#pragma unroll
          for (int j = 0; j < 4; j++) o_[dt][j] *= scb[j];
      }
      float t = 0.f;
#pragma unroll
      for (int ct = 0; ct < 4; ct++)
#pragma unroll
        for (int j = 0; j < 4; j++) {
          float p = __expf(sv[ct][j] - m_);
          sv[ct][j] = p;
          t += p;
        }
      t += __shfl_xor(t, 16);
      t += __shfl_xor(t, 32);
      l_ += t;
      if (kb < 8) vs_ += t;
      // ---- P -> LDS (same-wave roundtrip) ----
#pragma unroll
      for (int ct = 0; ct < 4; ct++) {
        uint2 pw;
        pw.x = (u32)f2bf(sv[ct][0]) | ((u32)f2bf(sv[ct][1]) << 16);
        pw.y = (u32)f2bf(sv[ct][2]) | ((u32)f2bf(sv[ct][3]) << 16);
        *(uint2*)(PlB + ((r * 128 + ct * 32 + g * 8) ^ ((r & 7) << 4))) = pw;
      }
      s16x8 pf[2];
#pragma unroll
      for (int kc = 0; kc < 2; kc++)
        pf[kc] = *(const s16x8*)(PlB + ((r * 128 + kc * 64 + g * 16) ^ ((r & 7) << 4)));
      // ---- O += P V ----
      __builtin_amdgcn_s_setprio(1);
#pragma unroll
      for (int dt = 0; dt < 8; dt++)
#pragma unroll
        for (int kc = 0; kc < 2; kc++) {
          int vbyte = (((dt * 16 + r) * 128) + kc * 64 + g * 16) ^ ((r & 7) << 4);
          o_[dt] = __builtin_amdgcn_mfma_f32_16x16x32_bf16(pf[kc], *(const s16x8*)(VB + vbyte), o_[dt], 0, 0, 0);
        }
      __builtin_amdgcn_s_setprio(0);
      FENCE();
      __builtin_amdgcn_s_barrier();  // readers done; next stage may overwrite
      FENCE();
      buf ^= 1;
    }
    // ---- epilogue for this q-tile ----
    float lb[4];
#pragma unroll
    for (int j = 0; j < 4; j++) lb[j] = 1.0f / __shfl(l_, g * 4 + j);
#pragma unroll
    for (int dt = 0; dt < 8; dt++)
#pragma unroll
      for (int j = 0; j < 4; j++) {
        int row = qb * 64 + w * 16 + g * 4 + j;
        int col = h * 128 + dt * 16 + r;
        AO[(size_t)row * 2048 + col] = f2bf(o_[dt][j] * lb[j]);
      }
    if (qb >= 8) {
      float acc = vs_ / l_;
#pragma unroll
      for (int off = 1; off < 64; off <<= 1) acc += __shfl_xor(acc, off);
      if (l == 0) atomicAdd(&cross[h], acc * (1.0f / (4.0f * 1536.0f)));
    }
  }
}

// ---------------- launcher ----------------
extern "C" void kernel_launch(void* const* d_in, const int* in_sizes, int n_in,
                              void* d_out, int out_size, void* d_ws, size_t ws_size,
                              hipStream_t stream) {
  const float* hs = (const float*)d_in[0];
  const float* wq = (const float*)d_in[1];
  const float* wk = (const float*)d_in[2];
  const float* wv = (const float*)d_in[3];
  const float* wo = (const float*)d_in[4];
  const float* qw = (const float*)d_in[5];
  const float* kw = (const float*)d_in[6];
  const float* cosT = (const float*)d_in[7];
  const float* sinT = (const float*)d_in[8];
  float* out = (float*)d_out;
  float* cross = out + (size_t)2048 * 2048;
  char* ws = (char*)d_ws;
  u16* hsb = (u16*)ws;                    //  0..8MB   hs bf16; later AO
  u16* wqkvT = (u16*)(ws + (8u << 20));   //  8..24MB  [wq|wk|wv]^T; later Qb/Kb/Vt
  u16* woT = (u16*)(ws + (24u << 20));    // 24..32MB  wo^T
  u16* qkvb = (u16*)(ws + (32u << 20));   // 32..48MB  qkv projection bf16
  u16* AO = hsb;
  u16* Qb = wqkvT;                        //  8..16MB
  u16* Kb = (u16*)(ws + (16u << 20));     // 16..20MB
  u16* Vt = (u16*)(ws + (20u << 20));     // 20..24MB  V^T [1024][2048]

  prep_k<<<16384, 256, 0, stream>>>(hs, hsb, wq, wk, wv, wo, wqkvT, woT);
  gemm3_k<256, 0><<<dim3(32, 8), 512, 0, stream>>>(hsb, wqkvT, qkvb, 4096, 2048);
  post_k<<<16896, 256, 0, stream>>>(qkvb, qw, kw, cosT, sinT, Qb, Kb, Vt, cross);
  attn_k<<<256, 256, 0, stream>>>(Qb, Kb, Vt, AO, cross);
  gemm3_k<128, 1><<<dim3(16, 16), 256, 0, stream>>>(AO, woT, out, 2048, 2048);
}

// Round 9
// 283.738 us; speedup vs baseline: 1.0660x; 1.0660x over previous
//
#include <hip/hip_runtime.h>
#include <hip/hip_bf16.h>
#include <stdint.h>

typedef unsigned short u16;
typedef unsigned int u32;
typedef short s16x8 __attribute__((ext_vector_type(8)));
typedef float f32x4 __attribute__((ext_vector_type(4)));

#define S_LEN 2048
#define SCALE 0.088388347648318447f
#define LOG2E 1.4426950408889634f
#define QSCALE (SCALE * LOG2E)
#define M2 17.5f   // fixed log2-domain max: |q.k|<=128 (RMS-normed) -> |s*log2e| <= 16.33 (+bf16 slack) < 17.5
#define NEG_BIG (-1.0e9f)
#define WAITV(N) asm volatile("s_waitcnt vmcnt(" #N ")" ::: "memory")
#define FENCE() asm volatile("" ::: "memory")
#define EXP2F(x) __builtin_amdgcn_exp2f(x)   // v_exp_f32: D = 2^S0

__device__ __forceinline__ u16 f2bf(float f) {
  unsigned u = __builtin_bit_cast(unsigned, f);
  u += 0x7fffu + ((u >> 16) & 1u);
  return (u16)(u >> 16);
}
__device__ __forceinline__ float bf2f(u16 h) {
  unsigned u = ((unsigned)h) << 16;
  return __builtin_bit_cast(float, u);
}
__device__ __forceinline__ void gload16(const void* g, void* l) {
  __builtin_amdgcn_global_load_lds((const __attribute__((address_space(1))) void*)g,
                                   (__attribute__((address_space(3))) void*)l, 16, 0, 0);
}

// ---------------- fused preprocessing: cvt(hs) + 4 weight transposes ----------------
__device__ __forceinline__ void do_transpose(const float* __restrict__ in, u16* __restrict__ out,
                                             int R, int C, int rel, int tilesx) {
  __shared__ float tile[32][33];
  int bx = (rel % tilesx) * 32, by = (rel / tilesx) * 32;
  int tx = threadIdx.x & 31, ty = threadIdx.x >> 5;
#pragma unroll
  for (int i = 0; i < 4; i++)
    tile[ty + i * 8][tx] = in[(size_t)(by + ty + i * 8) * C + bx + tx];
  __syncthreads();
#pragma unroll
  for (int i = 0; i < 4; i++)
    out[(size_t)(bx + ty + i * 8) * R + by + tx] = f2bf(tile[tx][ty + i * 8]);
}

__global__ __launch_bounds__(256) void prep_k(const float* __restrict__ hs, u16* __restrict__ hsb,
                                              const float* __restrict__ wq, const float* __restrict__ wk,
                                              const float* __restrict__ wv, const float* __restrict__ wo,
                                              u16* __restrict__ wqkvT, u16* __restrict__ woT) {
  int bid = blockIdx.x;
  if (bid < 4096) {
    int i = bid * 256 + threadIdx.x;
    float4 v = ((const float4*)hs)[i];
    ushort4 o;
    o.x = f2bf(v.x); o.y = f2bf(v.y); o.z = f2bf(v.z); o.w = f2bf(v.w);
    ((ushort4*)hsb)[i] = o;
  } else if (bid < 8192) {
    do_transpose(wq, wqkvT, 2048, 2048, bid - 4096, 64);
  } else if (bid < 10240) {
    do_transpose(wk, wqkvT + (size_t)2048 * 2048, 2048, 1024, bid - 8192, 32);
  } else if (bid < 12288) {
    do_transpose(wv, wqkvT + (size_t)3072 * 2048, 2048, 1024, bid - 10240, 32);
  } else {
    do_transpose(wo, woT, 2048, 2048, bid - 12288, 64);
  }
}

// ---------------- GEMM: C[M,N] = A[M,K] * BT[N,K]^T, BN=128, BK=64, counted-vmcnt dbuf ----------------
template <int BM, int F32OUT>
__global__ __launch_bounds__(BM == 256 ? 512 : 256, 2) void gemm2_k(const u16* __restrict__ A,
                                                                    const u16* __restrict__ BT,
                                                                    void* __restrict__ Cout, int N, int K) {
  constexpr int NT = (BM == 256) ? 512 : 256;
  constexpr int ALOADS = BM * 8 / NT;    // 4
  constexpr int BLOADS = 128 * 8 / NT;   // 2 or 4
  __shared__ u16 lA[2][BM * 64];
  __shared__ u16 lB[2][128 * 64];
  int tid = threadIdx.x;
  int w = tid >> 6, l = tid & 63, r = l & 15, g = l >> 4;
  int tn = blockIdx.x, tm = blockIdx.y;
  int wm = w >> 1, wn = w & 1;
  f32x4 zf = {0.f, 0.f, 0.f, 0.f};
  f32x4 acc[4][4];
#pragma unroll
  for (int mi = 0; mi < 4; mi++)
#pragma unroll
    for (int ni = 0; ni < 4; ni++) acc[mi][ni] = zf;
  int nkt = K >> 6;

  auto stage = [&](int bi, int kt) {
#pragma unroll
    for (int i = 0; i < ALOADS; i++) {
      int c = i * NT + tid;
      int row = c >> 3;
      int sb = ((c & 7) * 16) ^ ((row & 7) << 4);
      gload16(A + (size_t)(tm * BM + row) * K + kt * 64 + (sb >> 1), (char*)(&lA[bi][0]) + c * 16);
    }
#pragma unroll
    for (int i = 0; i < BLOADS; i++) {
      int c = i * NT + tid;
      int row = c >> 3;
      int sb = ((c & 7) * 16) ^ ((row & 7) << 4);
      gload16(BT + (size_t)(tn * 128 + row) * K + kt * 64 + (sb >> 1), (char*)(&lB[bi][0]) + c * 16);
    }
  };
  auto compute = [&](int bi) {
    const char* AB = (const char*)&lA[bi][0];
    const char* BB = (const char*)&lB[bi][0];
#pragma unroll
    for (int kk = 0; kk < 2; kk++) {
      s16x8 af[4], bfr[4];
#pragma unroll
      for (int mi = 0; mi < 4; mi++) {
        int row = wm * 64 + mi * 16 + r;
        af[mi] = *(const s16x8*)(AB + ((row * 128 + kk * 64 + g * 16) ^ ((r & 7) << 4)));
      }
#pragma unroll
      for (int ni = 0; ni < 4; ni++) {
        int row = wn * 64 + ni * 16 + r;
        bfr[ni] = *(const s16x8*)(BB + ((row * 128 + kk * 64 + g * 16) ^ ((r & 7) << 4)));
      }
#pragma unroll
      for (int mi = 0; mi < 4; mi++)
#pragma unroll
        for (int ni = 0; ni < 4; ni++)
          acc[mi][ni] = __builtin_amdgcn_mfma_f32_16x16x32_bf16(af[mi], bfr[ni], acc[mi][ni], 0, 0, 0);
    }
  };

  stage(0, 0);
  int cur = 0;
  for (int kt = 0; kt < nkt; ++kt) {
    if (kt + 1 < nkt) {
      stage(cur ^ 1, kt + 1);
      if (BM == 256) WAITV(6); else WAITV(8);
    } else {
      WAITV(0);
    }
    FENCE();
    __builtin_amdgcn_s_barrier();
    FENCE();
    __builtin_amdgcn_s_setprio(1);
    compute(cur);
    __builtin_amdgcn_s_setprio(0);
    FENCE();
    __builtin_amdgcn_s_barrier();
    FENCE();
    cur ^= 1;
  }

#pragma unroll
  for (int mi = 0; mi < 4; mi++) {
#pragma unroll
    for (int ni = 0; ni < 4; ni++) {
#pragma unroll
      for (int j = 0; j < 4; j++) {
        int row = tm * BM + wm * 64 + mi * 16 + g * 4 + j;
        int col = tn * 128 + wn * 64 + ni * 16 + r;
        if (F32OUT)
          ((float*)Cout)[(size_t)row * N + col] = acc[mi][ni][j];
        else
          ((u16*)Cout)[(size_t)row * N + col] = f2bf(acc[mi][ni][j]);
      }
    }
  }
}

// ---------------- fused post: RMSNorm+RoPE (Q pre-scaled to log2 domain, K), V transpose ----------------
__global__ __launch_bounds__(256) void post_k(const u16* __restrict__ qkv, const float* __restrict__ qw,
                                              const float* __restrict__ kw, const float* __restrict__ cosT,
                                              const float* __restrict__ sinT, u16* __restrict__ Qb,
                                              u16* __restrict__ Kb, u16* __restrict__ Vt,
                                              float* __restrict__ cross) {
  int bid = blockIdx.x;
  int tid = threadIdx.x;
  if (bid == 0 && tid < 16) cross[tid] = 0.f;
  if (bid < 16384) {
    int gw = bid * 4 + (tid >> 6);
    int l = tid & 63;
    int s = gw >> 5, slot = gw & 31;
    if (slot >= 24) return;
    const float* nw;
    const u16* src;
    u16* dst;
    float qs;
    if (slot < 16) {
      src = qkv + (size_t)s * 4096 + slot * 128;
      nw = qw;
      dst = Qb + ((size_t)slot * S_LEN + s) * 128;
      qs = QSCALE;  // fold 1/sqrt(D) * log2(e) into Q -> scores in exp2 domain
    } else {
      int hk = slot - 16;
      src = qkv + (size_t)s * 4096 + 2048 + hk * 128;
      nw = kw;
      dst = Kb + ((size_t)hk * S_LEN + s) * 128;
      qs = 1.0f;
    }
    ushort2 xv = ((const ushort2*)src)[l];
    float x0 = bf2f(xv.x), x1 = bf2f(xv.y);
    float ss = x0 * x0 + x1 * x1;
#pragma unroll
    for (int off = 1; off < 64; off <<= 1) ss += __shfl_xor(ss, off);
    float inv = rsqrtf(ss * (1.0f / 128.0f) + 1e-6f);
    int d0 = l * 2;
    float xn0 = x0 * inv * nw[d0], xn1 = x1 * inv * nw[d0 + 1];
    float p0 = __shfl_xor(xn0, 32), p1 = __shfl_xor(xn1, 32);
    float c0 = cosT[s * 128 + d0], c1 = cosT[s * 128 + d0 + 1];
    float sn0 = sinT[s * 128 + d0], sn1 = sinT[s * 128 + d0 + 1];
    float sg = (l < 32) ? -1.0f : 1.0f;
    ushort2 o;
    o.x = f2bf((xn0 * c0 + sg * p0 * sn0) * qs);
    o.y = f2bf((xn1 * c1 + sg * p1 * sn1) * qs);
    ((ushort2*)dst)[l] = o;
  } else {
    __shared__ u16 t[64][66];
    int rel = bid - 16384;
    int c0 = (rel & 15) * 64, s0 = (rel >> 4) * 64;
    int tx = tid & 63, ty = tid >> 6;
#pragma unroll
    for (int i = 0; i < 16; i++)
      t[ty + i * 4][tx] = qkv[(size_t)(s0 + ty + i * 4) * 4096 + 3072 + c0 + tx];
    __syncthreads();
#pragma unroll
    for (int i = 0; i < 16; i++)
      Vt[(size_t)(c0 + ty + i * 4) * 2048 + s0 + tx] = t[tx][ty + i * 4];
  }
}

// ---------------- flash attention + cross-score ----------------
// 512 blocks, interleaved short/long q-tiles per 16-bid group (R5-proven mapping).
// Swapped QK^T; FIXED-MAX softmax in exp2 domain: no running max, no rescale, no per-iter
// cross-lane reductions -- l/vs accumulate per-lane, reduced once in the epilogue.
__global__ __launch_bounds__(256, 2) void attn_k(const u16* __restrict__ Qb, const u16* __restrict__ Kb,
                                                 const u16* __restrict__ Vt, u16* __restrict__ AO,
                                                 float* __restrict__ cross) {
  __shared__ u16 Kl[2][64 * 128];
  __shared__ u16 Vl[2][128 * 64];
  __shared__ u16 Pl[4][16 * 64];
  int tid = threadIdx.x;
  int w = tid >> 6, l = tid & 63, r = l & 15, g = l >> 4;
  int bid = blockIdx.x;
  int sel = (bid >> 4) & 1;
  int idx = (bid & 15) | ((bid >> 5) << 4);
  int h = idx & 15, a = idx >> 4;
  int qb = sel ? (31 - a) : a;
  int hk = h >> 1;
  char* PlB = (char*)(&Pl[w][0]);

  int skrow = tid >> 4;
  int skoff = (tid & 15) * 16;
  int svrow = tid >> 3;
  int svoff = (tid & 7) * 16;
  auto stage = [&](int bi, int kb) {
#pragma unroll
    for (int i = 0; i < 4; i++) {
      int k = i * 16 + skrow;
      int sb = skoff ^ ((k & 7) << 4);
      gload16(Kb + (((size_t)hk * S_LEN + kb * 64 + k) << 7) + (sb >> 1),
              (char*)(&Kl[bi][0]) + (i * 256 + tid) * 16);
    }
#pragma unroll
    for (int i = 0; i < 4; i++) {
      int d = i * 32 + svrow;
      int sb = svoff ^ ((d & 7) << 4);
      gload16(Vt + (((size_t)hk * 128 + d) << 11) + kb * 64 + (sb >> 1),
              (char*)(&Vl[bi][0]) + (i * 256 + tid) * 16);
    }
  };

  int qrow = qb * 64 + w * 16 + r;
  s16x8 qf[4];
#pragma unroll
  for (int kc = 0; kc < 4; kc++)
    qf[kc] = *(const s16x8*)&Qb[((size_t)h * S_LEN + qrow) * 128 + kc * 32 + g * 8];
  f32x4 zf = {0.f, 0.f, 0.f, 0.f};
  f32x4 o_[8];
#pragma unroll
  for (int dt = 0; dt < 8; dt++) o_[dt] = zf;
  float l_ = 0.f, vs_ = 0.f;  // per-lane partial sums (lane covers 16 of 64 k per tile)

  stage(0, 0);
  int buf = 0;
  for (int kb = 0; kb <= qb; ++kb) {
    if (kb < qb) {
      stage(buf ^ 1, kb + 1);
      WAITV(8);
    } else {
      WAITV(0);
    }
    FENCE();
    __builtin_amdgcn_s_barrier();
    FENCE();
    const char* KB = (const char*)&Kl[buf][0];
    const char* VB = (const char*)&Vl[buf][0];
    // ---- S^T = K Q^T (exp2 domain, pre-scaled Q) ----
    f32x4 sa[4];
    __builtin_amdgcn_s_setprio(1);
#pragma unroll
    for (int ct = 0; ct < 4; ct++) {
      sa[ct] = zf;
#pragma unroll
      for (int kc = 0; kc < 4; kc++) {
        int kbyte = (((ct * 16 + r) * 256) + kc * 64 + g * 16) ^ ((r & 7) << 4);
        sa[ct] = __builtin_amdgcn_mfma_f32_16x16x32_bf16(*(const s16x8*)(KB + kbyte), qf[kc], sa[ct], 0, 0, 0);
      }
    }
    __builtin_amdgcn_s_setprio(0);
    // ---- fixed-max softmax: P = 2^(s - M2); no max tracking, no rescale ----
    float sv[4][4];
    float t = 0.f;
    if (kb == qb) {
      int kb0 = kb * 64 + g * 4;
#pragma unroll
      for (int ct = 0; ct < 4; ct++)
#pragma unroll
        for (int j = 0; j < 4; j++) {
          float x = sa[ct][j] + ((kb0 + ct * 16 + j) > qrow ? NEG_BIG : 0.f);
          float p = EXP2F(x - M2);
          sv[ct][j] = p;
          t += p;
        }
    } else {
#pragma unroll
      for (int ct = 0; ct < 4; ct++)
#pragma unroll
        for (int j = 0; j < 4; j++) {
          float p = EXP2F(sa[ct][j] - M2);
          sv[ct][j] = p;
          t += p;
        }
    }
    l_ += t;
    if (kb < 8) vs_ += t;  // kv block entirely vision (k < 512)
    // ---- P -> LDS (cvt_pk pack, same-wave roundtrip) ----
#pragma unroll
    for (int ct = 0; ct < 4; ct++) {
      u32 lo, hi;
      asm("v_cvt_pk_bf16_f32 %0, %1, %2" : "=v"(lo) : "v"(sv[ct][0]), "v"(sv[ct][1]));
      asm("v_cvt_pk_bf16_f32 %0, %1, %2" : "=v"(hi) : "v"(sv[ct][2]), "v"(sv[ct][3]));
      uint2 pw;
      pw.x = lo;
      pw.y = hi;
      *(uint2*)(PlB + ((r * 128 + ct * 32 + g * 8) ^ ((r & 7) << 4))) = pw;
    }
    s16x8 pf[2];
#pragma unroll
    for (int kc = 0; kc < 2; kc++)
      pf[kc] = *(const s16x8*)(PlB + ((r * 128 + kc * 64 + g * 16) ^ ((r & 7) << 4)));
    // ---- O += P V ----
    __builtin_amdgcn_s_setprio(1);
#pragma unroll
    for (int dt = 0; dt < 8; dt++)
#pragma unroll
      for (int kc = 0; kc < 2; kc++) {
        int vbyte = (((dt * 16 + r) * 128) + kc * 64 + g * 16) ^ ((r & 7) << 4);
        o_[dt] = __builtin_amdgcn_mfma_f32_16x16x32_bf16(pf[kc], *(const s16x8*)(VB + vbyte), o_[dt], 0, 0, 0);
      }
    __builtin_amdgcn_s_setprio(0);
    FENCE();
    __builtin_amdgcn_s_barrier();
    FENCE();
    buf ^= 1;
  }
  // ---- epilogue: reduce per-lane partials across the 4 g-replicas, then normalize ----
  l_ += __shfl_xor(l_, 16);
  l_ += __shfl_xor(l_, 32);
  vs_ += __shfl_xor(vs_, 16);
  vs_ += __shfl_xor(vs_, 32);
  float lb[4];
#pragma unroll
  for (int j = 0; j < 4; j++) lb[j] = 1.0f / __shfl(l_, g * 4 + j);
#pragma unroll
  for (int dt = 0; dt < 8; dt++)
#pragma unroll
    for (int j = 0; j < 4; j++) {
      int row = qb * 64 + w * 16 + g * 4 + j;
      int col = h * 128 + dt * 16 + r;
      AO[(size_t)row * 2048 + col] = f2bf(o_[dt][j] * lb[j]);
    }
  if (qb >= 8) {  // all rows text queries (q >= 512)
    float acc = vs_ / l_;  // replicated 4x across g per q-row
#pragma unroll
    for (int off = 1; off < 64; off <<= 1) acc += __shfl_xor(acc, off);
    if (l == 0) atomicAdd(&cross[h], acc * (1.0f / (4.0f * 1536.0f)));
  }
}

// ---------------- launcher ----------------
extern "C" void kernel_launch(void* const* d_in, const int* in_sizes, int n_in,
                              void* d_out, int out_size, void* d_ws, size_t ws_size,
                              hipStream_t stream) {
  const float* hs = (const float*)d_in[0];
  const float* wq = (const float*)d_in[1];
  const float* wk = (const float*)d_in[2];
  const float* wv = (const float*)d_in[3];
  const float* wo = (const float*)d_in[4];
  const float* qw = (const float*)d_in[5];
  const float* kw = (const float*)d_in[6];
  const float* cosT = (const float*)d_in[7];
  const float* sinT = (const float*)d_in[8];
  float* out = (float*)d_out;
  float* cross = out + (size_t)2048 * 2048;
  char* ws = (char*)d_ws;
  u16* hsb = (u16*)ws;                    //  0..8MB   hs bf16; later AO
  u16* wqkvT = (u16*)(ws + (8u << 20));   //  8..24MB  [wq|wk|wv]^T; later Qb/Kb/Vt
  u16* woT = (u16*)(ws + (24u << 20));    // 24..32MB  wo^T
  u16* qkvb = (u16*)(ws + (32u << 20));   // 32..48MB  qkv projection bf16
  u16* AO = hsb;
  u16* Qb = wqkvT;                        //  8..16MB
  u16* Kb = (u16*)(ws + (16u << 20));     // 16..20MB
  u16* Vt = (u16*)(ws + (20u << 20));     // 20..24MB  V^T [1024][2048]

  prep_k<<<16384, 256, 0, stream>>>(hs, hsb, wq, wk, wv, wo, wqkvT, woT);
  gemm2_k<256, 0><<<dim3(32, 8), 512, 0, stream>>>(hsb, wqkvT, qkvb, 4096, 2048);
  post_k<<<16896, 256, 0, stream>>>(qkvb, qw, kw, cosT, sinT, Qb, Kb, Vt, cross);
  attn_k<<<512, 256, 0, stream>>>(Qb, Kb, Vt, AO, cross);
  gemm2_k<128, 1><<<dim3(16, 16), 256, 0, stream>>>(AO, woT, out, 2048, 2048);
}

// Round 11
// 271.191 us; speedup vs baseline: 1.1153x; 1.0463x over previous
//
#include <hip/hip_runtime.h>
#include <hip/hip_bf16.h>
#include <stdint.h>

typedef unsigned short u16;
typedef unsigned int u32;
typedef short s16x8 __attribute__((ext_vector_type(8)));
typedef float f32x4 __attribute__((ext_vector_type(4)));

#define S_LEN 2048
#define SCALE 0.088388347648318447f
#define LOG2E 1.4426950408889634f
#define QSCALE (SCALE * LOG2E)
#define M2 17.5f   // fixed log2-domain max: RMS-normed q,k -> |s*log2e| <= 16.33 < 17.5
#define NEG_BIG (-1.0e9f)
#define WAITV(N) asm volatile("s_waitcnt vmcnt(" #N ")" ::: "memory")
#define FENCE() asm volatile("" ::: "memory")
#define EXP2F(x) __builtin_amdgcn_exp2f(x)   // v_exp_f32: D = 2^S0

__device__ __forceinline__ u16 f2bf(float f) {
  unsigned u = __builtin_bit_cast(unsigned, f);
  u += 0x7fffu + ((u >> 16) & 1u);
  return (u16)(u >> 16);
}
__device__ __forceinline__ float bf2f(u16 h) {
  unsigned u = ((unsigned)h) << 16;
  return __builtin_bit_cast(float, u);
}
__device__ __forceinline__ void gload16(const void* g, void* l) {
  __builtin_amdgcn_global_load_lds((const __attribute__((address_space(1))) void*)g,
                                   (__attribute__((address_space(3))) void*)l, 16, 0, 0);
}

// ---------------- fused preprocessing: cvt(hs) + 4 weight transposes (64x64 tiles) ----------------
__device__ __forceinline__ void do_transpose64(const float* __restrict__ in, u16* __restrict__ out,
                                               int R, int C, int rel, int tilesx) {
  __shared__ float tile[64][65];
  int bx = (rel % tilesx) * 64, by = (rel / tilesx) * 64;
  int c = threadIdx.x & 63, rr = threadIdx.x >> 6;
#pragma unroll
  for (int i = 0; i < 16; i++) {
    int r = rr + i * 4;
    tile[c][r] = in[(size_t)(by + r) * C + bx + c];
  }
  __syncthreads();
  int sp = threadIdx.x & 31, cc0 = threadIdx.x >> 5;
#pragma unroll
  for (int i = 0; i < 8; i++) {
    int cc = cc0 + i * 8;
    ushort2 o;
    o.x = f2bf(tile[cc][2 * sp]);
    o.y = f2bf(tile[cc][2 * sp + 1]);
    *(ushort2*)&out[(size_t)(bx + cc) * R + by + 2 * sp] = o;
  }
}

__global__ __launch_bounds__(256) void prep_k(const float* __restrict__ hs, u16* __restrict__ hsb,
                                              const float* __restrict__ wq, const float* __restrict__ wk,
                                              const float* __restrict__ wv, const float* __restrict__ wo,
                                              u16* __restrict__ wqkvT, u16* __restrict__ woT) {
  int bid = blockIdx.x;
  if (bid < 4096) {  // fp32 -> bf16 of hidden_states
    int i = bid * 256 + threadIdx.x;
    float4 v = ((const float4*)hs)[i];
    ushort4 o;
    o.x = f2bf(v.x); o.y = f2bf(v.y); o.z = f2bf(v.z); o.w = f2bf(v.w);
    ((ushort4*)hsb)[i] = o;
  } else if (bid < 5120) {
    do_transpose64(wq, wqkvT, 2048, 2048, bid - 4096, 32);
  } else if (bid < 5632) {
    do_transpose64(wk, wqkvT + (size_t)2048 * 2048, 2048, 1024, bid - 5120, 16);
  } else if (bid < 6144) {
    do_transpose64(wv, wqkvT + (size_t)3072 * 2048, 2048, 1024, bid - 5632, 16);
  } else {
    do_transpose64(wo, woT, 2048, 2048, bid - 6144, 32);
  }
}

// ---------------- GEMM (R3-proven): C[M,N] = A[M,K] * BT[N,K]^T, 128x128, BK=64, syncthreads dbuf ----------------
template <int F32OUT>
__global__ __launch_bounds__(256, 2) void gemm_bt_k(const u16* __restrict__ A, const u16* __restrict__ BT,
                                                    void* __restrict__ Cout, int N, int K) {
  __shared__ u16 lA[2][128 * 64];
  __shared__ u16 lB[2][128 * 64];
  int tid = threadIdx.x;
  int w = tid >> 6, l = tid & 63, r = l & 15, g = l >> 4;
  int tn = blockIdx.x, tm = blockIdx.y;
  int wm = w >> 1, wn = w & 1;
  f32x4 zf = {0.f, 0.f, 0.f, 0.f};
  f32x4 acc[4][4];
#pragma unroll
  for (int mi = 0; mi < 4; mi++)
#pragma unroll
    for (int ni = 0; ni < 4; ni++) acc[mi][ni] = zf;
  int nkt = K >> 6;

  int srow = tid >> 3;
  int soff = (tid & 7) * 16;
  auto stage = [&](int bi, int kt) {
#pragma unroll
    for (int i = 0; i < 4; i++) {
      int row = i * 32 + srow;
      int sb = soff ^ ((row & 7) << 4);
      int L = (i * 256 + tid) * 16;
      gload16(A + (size_t)(tm * 128 + row) * K + kt * 64 + (sb >> 1), (char*)(&lA[bi][0]) + L);
      gload16(BT + (size_t)(tn * 128 + row) * K + kt * 64 + (sb >> 1), (char*)(&lB[bi][0]) + L);
    }
  };
  auto compute = [&](int bi) {
    const char* AB = (const char*)&lA[bi][0];
    const char* BB = (const char*)&lB[bi][0];
#pragma unroll
    for (int kk = 0; kk < 2; kk++) {
      s16x8 af[4], bfr[4];
#pragma unroll
      for (int mi = 0; mi < 4; mi++) {
        int row = wm * 64 + mi * 16 + r;
        af[mi] = *(const s16x8*)(AB + ((row * 128 + kk * 64 + g * 16) ^ ((r & 7) << 4)));
      }
#pragma unroll
      for (int ni = 0; ni < 4; ni++) {
        int row = wn * 64 + ni * 16 + r;
        bfr[ni] = *(const s16x8*)(BB + ((row * 128 + kk * 64 + g * 16) ^ ((r & 7) << 4)));
      }
#pragma unroll
      for (int mi = 0; mi < 4; mi++)
#pragma unroll
        for (int ni = 0; ni < 4; ni++)
          acc[mi][ni] = __builtin_amdgcn_mfma_f32_16x16x32_bf16(af[mi], bfr[ni], acc[mi][ni], 0, 0, 0);
    }
  };

  stage(0, 0);
  __syncthreads();
  int cur = 0;
  for (int kt = 0; kt + 1 < nkt; ++kt) {
    stage(cur ^ 1, kt + 1);  // prefetch next tile; latency hides under compute
    compute(cur);
    __syncthreads();         // drains vmcnt + lgkmcnt
    cur ^= 1;
  }
  compute(cur);

#pragma unroll
  for (int mi = 0; mi < 4; mi++) {
#pragma unroll
    for (int ni = 0; ni < 4; ni++) {
#pragma unroll
      for (int j = 0; j < 4; j++) {
        int row = tm * 128 + wm * 64 + mi * 16 + g * 4 + j;
        int col = tn * 128 + wn * 64 + ni * 16 + r;
        if (F32OUT)
          ((float*)Cout)[(size_t)row * N + col] = acc[mi][ni][j];
        else
          ((u16*)Cout)[(size_t)row * N + col] = f2bf(acc[mi][ni][j]);
      }
    }
  }
}

// ---------------- fused post: RMSNorm+RoPE (Q pre-scaled to log2 domain, K), V transpose ----------------
__global__ __launch_bounds__(256) void post_k(const u16* __restrict__ qkv, const float* __restrict__ qw,
                                              const float* __restrict__ kw, const float* __restrict__ cosT,
                                              const float* __restrict__ sinT, u16* __restrict__ Qb,
                                              u16* __restrict__ Kb, u16* __restrict__ Vt,
                                              float* __restrict__ cross) {
  int bid = blockIdx.x;
  int tid = threadIdx.x;
  if (bid == 0 && tid < 16) cross[tid] = 0.f;
  if (bid < 16384) {
    int gw = bid * 4 + (tid >> 6);
    int l = tid & 63;
    int s = gw >> 5, slot = gw & 31;
    if (slot >= 24) return;
    const float* nw;
    const u16* src;
    u16* dst;
    float qs;
    if (slot < 16) {
      src = qkv + (size_t)s * 4096 + slot * 128;
      nw = qw;
      dst = Qb + ((size_t)slot * S_LEN + s) * 128;
      qs = QSCALE;  // fold 1/sqrt(D) * log2(e) into Q -> scores in exp2 domain
    } else {
      int hk = slot - 16;
      src = qkv + (size_t)s * 4096 + 2048 + hk * 128;
      nw = kw;
      dst = Kb + ((size_t)hk * S_LEN + s) * 128;
      qs = 1.0f;
    }
    ushort2 xv = ((const ushort2*)src)[l];
    float x0 = bf2f(xv.x), x1 = bf2f(xv.y);
    float ss = x0 * x0 + x1 * x1;
#pragma unroll
    for (int off = 1; off < 64; off <<= 1) ss += __shfl_xor(ss, off);
    float inv = rsqrtf(ss * (1.0f / 128.0f) + 1e-6f);
    int d0 = l * 2;
    float xn0 = x0 * inv * nw[d0], xn1 = x1 * inv * nw[d0 + 1];
    float p0 = __shfl_xor(xn0, 32), p1 = __shfl_xor(xn1, 32);
    float c0 = cosT[s * 128 + d0], c1 = cosT[s * 128 + d0 + 1];
    float sn0 = sinT[s * 128 + d0], sn1 = sinT[s * 128 + d0 + 1];
    float sg = (l < 32) ? -1.0f : 1.0f;
    ushort2 o;
    o.x = f2bf((xn0 * c0 + sg * p0 * sn0) * qs);
    o.y = f2bf((xn1 * c1 + sg * p1 * sn1) * qs);
    ((ushort2*)dst)[l] = o;
  } else {
    __shared__ u16 t[64][66];
    int rel = bid - 16384;
    int c0 = (rel & 15) * 64, s0 = (rel >> 4) * 64;
    int tx = tid & 63, ty = tid >> 6;
#pragma unroll
    for (int i = 0; i < 16; i++)
      t[ty + i * 4][tx] = qkv[(size_t)(s0 + ty + i * 4) * 4096 + 3072 + c0 + tx];
    __syncthreads();
#pragma unroll
    for (int i = 0; i < 16; i++)
      Vt[(size_t)(c0 + ty + i * 4) * 2048 + s0 + tx] = t[tx][ty + i * 4];
  }
}

// ---------------- flash attention + cross-score (R9 structure + tree-sum) ----------------
__global__ __launch_bounds__(256, 2) void attn_k(const u16* __restrict__ Qb, const u16* __restrict__ Kb,
                                                 const u16* __restrict__ Vt, u16* __restrict__ AO,
                                                 float* __restrict__ cross) {
  __shared__ u16 Kl[2][64 * 128];
  __shared__ u16 Vl[2][128 * 64];
  __shared__ u16 Pl[4][16 * 64];
  int tid = threadIdx.x;
  int w = tid >> 6, l = tid & 63, r = l & 15, g = l >> 4;
  int bid = blockIdx.x;
  int sel = (bid >> 4) & 1;
  int idx = (bid & 15) | ((bid >> 5) << 4);
  int h = idx & 15, a = idx >> 4;
  int qb = sel ? (31 - a) : a;
  int hk = h >> 1;
  char* PlB = (char*)(&Pl[w][0]);

  int skrow = tid >> 4;
  int skoff = (tid & 15) * 16;
  int svrow = tid >> 3;
  int svoff = (tid & 7) * 16;
  auto stage = [&](int bi, int kb) {
#pragma unroll
    for (int i = 0; i < 4; i++) {
      int k = i * 16 + skrow;
      int sb = skoff ^ ((k & 7) << 4);
      gload16(Kb + (((size_t)hk * S_LEN + kb * 64 + k) << 7) + (sb >> 1),
              (char*)(&Kl[bi][0]) + (i * 256 + tid) * 16);
    }
#pragma unroll
    for (int i = 0; i < 4; i++) {
      int d = i * 32 + svrow;
      int sb = svoff ^ ((d & 7) << 4);
      gload16(Vt + (((size_t)hk * 128 + d) << 11) + kb * 64 + (sb >> 1),
              (char*)(&Vl[bi][0]) + (i * 256 + tid) * 16);
    }
  };

  int qrow = qb * 64 + w * 16 + r;
  s16x8 qf[4];
#pragma unroll
  for (int kc = 0; kc < 4; kc++)
    qf[kc] = *(const s16x8*)&Qb[((size_t)h * S_LEN + qrow) * 128 + kc * 32 + g * 8];
  f32x4 zf = {0.f, 0.f, 0.f, 0.f};
  f32x4 o_[8];
#pragma unroll
  for (int dt = 0; dt < 8; dt++) o_[dt] = zf;
  float l_ = 0.f, vs_ = 0.f;  // per-lane partial sums; reduced once in epilogue

  stage(0, 0);
  int buf = 0;
  for (int kb = 0; kb <= qb; ++kb) {
    if (kb < qb) {
      stage(buf ^ 1, kb + 1);
      WAITV(8);
    } else {
      WAITV(0);
    }
    FENCE();
    __builtin_amdgcn_s_barrier();
    FENCE();
    const char* KB = (const char*)&Kl[buf][0];
    const char* VB = (const char*)&Vl[buf][0];
    // ---- S^T = K Q^T (exp2 domain, pre-scaled Q) ----
    f32x4 sa[4];
    __builtin_amdgcn_s_setprio(1);
#pragma unroll
    for (int ct = 0; ct < 4; ct++) {
      sa[ct] = zf;
#pragma unroll
      for (int kc = 0; kc < 4; kc++) {
        int kbyte = (((ct * 16 + r) * 256) + kc * 64 + g * 16) ^ ((r & 7) << 4);
        sa[ct] = __builtin_amdgcn_mfma_f32_16x16x32_bf16(*(const s16x8*)(KB + kbyte), qf[kc], sa[ct], 0, 0, 0);
      }
    }
    __builtin_amdgcn_s_setprio(0);
    // ---- fixed-max softmax: P = 2^(s - M2); tree-summed partials ----
    float sv[4][4];
    float tct[4];
    if (kb == qb) {
      int kb0 = kb * 64 + g * 4;
#pragma unroll
      for (int ct = 0; ct < 4; ct++) {
#pragma unroll
        for (int j = 0; j < 4; j++) {
          float x = sa[ct][j] + ((kb0 + ct * 16 + j) > qrow ? NEG_BIG : 0.f);
          sv[ct][j] = EXP2F(x - M2);
        }
        tct[ct] = (sv[ct][0] + sv[ct][1]) + (sv[ct][2] + sv[ct][3]);
      }
    } else {
#pragma unroll
      for (int ct = 0; ct < 4; ct++) {
#pragma unroll
        for (int j = 0; j < 4; j++) sv[ct][j] = EXP2F(sa[ct][j] - M2);
        tct[ct] = (sv[ct][0] + sv[ct][1]) + (sv[ct][2] + sv[ct][3]);
      }
    }
    float t = (tct[0] + tct[1]) + (tct[2] + tct[3]);
    l_ += t;
    if (kb < 8) vs_ += t;  // kv block entirely vision (k < 512)
    // ---- P -> LDS (cvt_pk pack, same-wave roundtrip) ----
#pragma unroll
    for (int ct = 0; ct < 4; ct++) {
      u32 lo, hi;
      asm("v_cvt_pk_bf16_f32 %0, %1, %2" : "=v"(lo) : "v"(sv[ct][0]), "v"(sv[ct][1]));
      asm("v_cvt_pk_bf16_f32 %0, %1, %2" : "=v"(hi) : "v"(sv[ct][2]), "v"(sv[ct][3]));
      uint2 pw;
      pw.x = lo;
      pw.y = hi;
      *(uint2*)(PlB + ((r * 128 + ct * 32 + g * 8) ^ ((r & 7) << 4))) = pw;
    }
    s16x8 pf[2];
#pragma unroll
    for (int kc = 0; kc < 2; kc++)
      pf[kc] = *(const s16x8*)(PlB + ((r * 128 + kc * 64 + g * 16) ^ ((r & 7) << 4)));
    // ---- O += P V ----
    __builtin_amdgcn_s_setprio(1);
#pragma unroll
    for (int dt = 0; dt < 8; dt++)
#pragma unroll
      for (int kc = 0; kc < 2; kc++) {
        int vbyte = (((dt * 16 + r) * 128) + kc * 64 + g * 16) ^ ((r & 7) << 4);
        o_[dt] = __builtin_amdgcn_mfma_f32_16x16x32_bf16(pf[kc], *(const s16x8*)(VB + vbyte), o_[dt], 0, 0, 0);
      }
    __builtin_amdgcn_s_setprio(0);
    FENCE();
    __builtin_amdgcn_s_barrier();
    FENCE();
    buf ^= 1;
  }
  // ---- epilogue: reduce per-lane partials across g-replicas, normalize ----
  l_ += __shfl_xor(l_, 16);
  l_ += __shfl_xor(l_, 32);
  vs_ += __shfl_xor(vs_, 16);
  vs_ += __shfl_xor(vs_, 32);
  float lb[4];
#pragma unroll
  for (int j = 0; j < 4; j++) lb[j] = 1.0f / __shfl(l_, g * 4 + j);
#pragma unroll
  for (int dt = 0; dt < 8; dt++)
#pragma unroll
    for (int j = 0; j < 4; j++) {
      int row = qb * 64 + w * 16 + g * 4 + j;
      int col = h * 128 + dt * 16 + r;
      AO[(size_t)row * 2048 + col] = f2bf(o_[dt][j] * lb[j]);
    }
  if (qb >= 8) {  // all rows text queries (q >= 512)
    float acc = vs_ / l_;  // replicated 4x across g per q-row
#pragma unroll
    for (int off = 1; off < 64; off <<= 1) acc += __shfl_xor(acc, off);
    if (l == 0) atomicAdd(&cross[h], acc * (1.0f / (4.0f * 1536.0f)));
  }
}

// ---------------- launcher ----------------
extern "C" void kernel_launch(void* const* d_in, const int* in_sizes, int n_in,
                              void* d_out, int out_size, void* d_ws, size_t ws_size,
                              hipStream_t stream) {
  const float* hs = (const float*)d_in[0];
  const float* wq = (const float*)d_in[1];
  const float* wk = (const float*)d_in[2];
  const float* wv = (const float*)d_in[3];
  const float* wo = (const float*)d_in[4];
  const float* qw = (const float*)d_in[5];
  const float* kw = (const float*)d_in[6];
  const float* cosT = (const float*)d_in[7];
  const float* sinT = (const float*)d_in[8];
  float* out = (float*)d_out;
  float* cross = out + (size_t)2048 * 2048;
  char* ws = (char*)d_ws;
  u16* hsb = (u16*)ws;                    //  0..8MB   hs bf16; later AO
  u16* wqkvT = (u16*)(ws + (8u << 20));   //  8..24MB  [wq|wk|wv]^T; later Qb/Kb/Vt
  u16* woT = (u16*)(ws + (24u << 20));    // 24..32MB  wo^T
  u16* qkvb = (u16*)(ws + (32u << 20));   // 32..48MB  qkv projection bf16
  u16* AO = hsb;
  u16* Qb = wqkvT;                        //  8..16MB
  u16* Kb = (u16*)(ws + (16u << 20));     // 16..20MB
  u16* Vt = (u16*)(ws + (20u << 20));     // 20..24MB  V^T [1024][2048]

  prep_k<<<7168, 256, 0, stream>>>(hs, hsb, wq, wk, wv, wo, wqkvT, woT);
  gemm_bt_k<0><<<dim3(32, 16), 256, 0, stream>>>(hsb, wqkvT, qkvb, 4096, 2048);
  post_k<<<16896, 256, 0, stream>>>(qkvb, qw, kw, cosT, sinT, Qb, Kb, Vt, cross);
  attn_k<<<512, 256, 0, stream>>>(Qb, Kb, Vt, AO, cross);
  gemm_bt_k<1><<<dim3(16, 16), 256, 0, stream>>>(AO, woT, out, 2048, 2048);
}